// Round 1
// 401.838 us; speedup vs baseline: 1.1058x; 1.1058x over previous
//
#include <hip/hip_runtime.h>

// GNN layer: messages = relu(NF @ Wm^T + bm); agg = (adj @ messages)/deg; GRU(agg, NF)
// N=8192, D=128. Roofline: adj read 268 MB @6.3TB/s = 43us. bf16 MFMA 16x16x32.
// V2: K2 k-split=2 (2 blocks/CU, f32 partials), K1 vectorized+full-grid+bf16 weight
// pre-convert, K3 barrier-free (B-frags direct from L2-resident bf16 weights).

#define NN 8192
#define DIM 128
#define LSTR 136  // 128 + 8 bf16 pad: 272B rows, 16B-aligned, conflict-light

typedef __bf16 bf16x8 __attribute__((ext_vector_type(8)));
typedef float f32x4 __attribute__((ext_vector_type(4)));

__device__ __forceinline__ unsigned short f2bf(float f) {
  union { float f; unsigned u; } v; v.f = f;
  unsigned r = v.u + 0x7FFF + ((v.u >> 16) & 1);  // RNE
  return (unsigned short)(r >> 16);
}
__device__ __forceinline__ ushort4 f2bf4(float4 f) {
  ushort4 u; u.x = f2bf(f.x); u.y = f2bf(f.y); u.z = f2bf(f.z); u.w = f2bf(f.w);
  return u;
}
__device__ __forceinline__ float sigmoidf_(float x) {
  return 1.0f / (1.0f + __expf(-x));
}
__device__ __forceinline__ float tanhf_(float x) {
  float e = __expf(-2.0f * fabsf(x));
  float r = (1.0f - e) / (1.0f + e);
  return x < 0.0f ? -r : r;
}

// ---------------- K1: msgT[o][m] = relu(NF @ Wm^T + bm) (bf16, transposed).
// Side jobs: nfB = bf16(nf) (for K3's gh GEMM A-operand), wihB/whhB = bf16 weights
// (converted ONCE here instead of per-block in K3). Grid 256 (full GPU), float4 staging.
__global__ __launch_bounds__(256) void k1_msg(
    const float* __restrict__ nf, const float* __restrict__ w_msg,
    const float* __restrict__ b_msg, unsigned short* __restrict__ msgT,
    unsigned short* __restrict__ nfB, const float* __restrict__ w_ih,
    const float* __restrict__ w_hh, unsigned short* __restrict__ wihB,
    unsigned short* __restrict__ whhB) {
  __shared__ unsigned short wm[128 * LSTR];   // wm[o][k] bf16
  __shared__ unsigned short nfl[32 * LSTR];   // nf tile [m][k] bf16
  const int t = threadIdx.x;
  const int m0 = blockIdx.x * 32;

  // once-per-launch weight conversion, spread over the grid (24576 float4 total)
  const int gtid = blockIdx.x * 256 + t;
  if (gtid < 12288) {
    ((ushort4*)wihB)[gtid] = f2bf4(((const float4*)w_ih)[gtid]);
  } else if (gtid < 24576) {
    ((ushort4*)whhB)[gtid - 12288] = f2bf4(((const float4*)w_hh)[gtid - 12288]);
  }
  // stage w_msg: 16384 f32 = 4096 float4
  for (int i = t; i < 4096; i += 256) {
    float4 v = ((const float4*)w_msg)[i];
    const int row = i >> 5, col = (i & 31) * 4;
    *(ushort4*)&wm[row * LSTR + col] = f2bf4(v);
  }
  // stage nf tile (1024 float4) + emit nfB
  for (int i = t; i < 1024; i += 256) {
    float4 v = ((const float4*)(nf + m0 * 128))[i];
    ushort4 u = f2bf4(v);
    const int row = i >> 5, col = (i & 31) * 4;
    *(ushort4*)&nfl[row * LSTR + col] = u;
    *(ushort4*)&nfB[(m0 + row) * 128 + col] = u;
  }
  __syncthreads();

  const int lane = t & 63, wave = t >> 6;
  const int quad = lane >> 4, l16 = lane & 15;
  const int rt = wave >> 1, ch = wave & 1;  // 2 row-tiles x 2 col-halves
  f32x4 acc[4];
  for (int j = 0; j < 4; ++j) acc[j] = (f32x4){0.f, 0.f, 0.f, 0.f};
  for (int kk = 0; kk < 4; ++kk) {
    bf16x8 a = *(const bf16x8*)&nfl[(rt * 16 + l16) * LSTR + kk * 32 + quad * 8];
    for (int j = 0; j < 4; ++j) {
      const int ct = ch * 4 + j;
      bf16x8 b = *(const bf16x8*)&wm[(ct * 16 + l16) * LSTR + kk * 32 + quad * 8];
      acc[j] = __builtin_amdgcn_mfma_f32_16x16x32_bf16(a, b, acc[j], 0, 0, 0);
    }
  }
  const int mb = m0 + rt * 16 + quad * 4;  // 4 consecutive m per lane -> ushort4 store
  for (int j = 0; j < 4; ++j) {
    const int o = (ch * 4 + j) * 16 + l16;
    const float bias = b_msg[o];
    ushort4 u;
    u.x = f2bf(fmaxf(acc[j][0] + bias, 0.0f));
    u.y = f2bf(fmaxf(acc[j][1] + bias, 0.0f));
    u.z = f2bf(fmaxf(acc[j][2] + bias, 0.0f));
    u.w = f2bf(fmaxf(acc[j][3] + bias, 0.0f));
    *(ushort4*)&msgT[o * NN + mb] = u;
  }
}

// ---------------- K2: aggP[ks][m][o] = sum_{k in half ks} adj[m][k]*msg[k][o] (f32),
// degP[ks][m] = row-degree partial. K-split=2 -> grid 512 = 2 blocks/CU: independent
// blocks overlap each other's barrier/HBM-latency stalls (was 1 block/CU lockstep).
__global__ __launch_bounds__(512) void k2_agg(
    const int* __restrict__ adj, const unsigned short* __restrict__ msgT,
    float* __restrict__ aggP, int* __restrict__ degP) {
  __shared__ unsigned short adjL[32 * LSTR];   // A tile [m][k] bf16 (0/1)
  __shared__ unsigned short msgL[128 * LSTR];  // B tile [o][k] bf16
  __shared__ int degS[32];
  const int t = threadIdx.x;
  const int m0 = (blockIdx.x & 255) * 32;
  const int ks = blockIdx.x >> 8;
  const int kbase = ks * 4096;
  if (t < 32) degS[t] = 0;

  const int ar = t >> 5;         // 0..15
  const int as = t & 31;         // int4 segment within row
  const int mn = t >> 4;         // 0..31
  const int mko = (t & 15) * 8;

  const int* aB0 = adj + (m0 + ar) * NN + kbase + as * 4;
  const int* aB1 = aB0 + 16 * NN;
  const unsigned short* mB0 = msgT + (mn +  0) * NN + kbase + mko;
  const unsigned short* mB1 = msgT + (mn + 32) * NN + kbase + mko;
  const unsigned short* mB2 = msgT + (mn + 64) * NN + kbase + mko;
  const unsigned short* mB3 = msgT + (mn + 96) * NN + kbase + mko;

  int deg0 = 0, deg1 = 0;
  int4 pa0 = *(const int4*)aB0;
  int4 pa1 = *(const int4*)aB1;
  int4 pm0 = *(const int4*)mB0;
  int4 pm1 = *(const int4*)mB1;
  int4 pm2 = *(const int4*)mB2;
  int4 pm3 = *(const int4*)mB3;

  const int lane = t & 63, wave = t >> 6;
  const int quad = lane >> 4, l16 = lane & 15;
  const int rt = wave >> 2;
  const int ct0 = (wave & 3) * 2, ct1 = ct0 + 1;
  f32x4 acc0 = {0.f, 0.f, 0.f, 0.f}, acc1 = {0.f, 0.f, 0.f, 0.f};

  const int aOff  = (rt * 16 + l16) * LSTR + quad * 8;
  const int bOff0 = (ct0 * 16 + l16) * LSTR + quad * 8;
  const int bOff1 = (ct1 * 16 + l16) * LSTR + quad * 8;

  for (int c = 0; c < 32; ++c) {
    ushort4 w0, w1;
    w0.x = pa0.x ? 0x3F80 : 0; w0.y = pa0.y ? 0x3F80 : 0;
    w0.z = pa0.z ? 0x3F80 : 0; w0.w = pa0.w ? 0x3F80 : 0;
    w1.x = pa1.x ? 0x3F80 : 0; w1.y = pa1.y ? 0x3F80 : 0;
    w1.z = pa1.z ? 0x3F80 : 0; w1.w = pa1.w ? 0x3F80 : 0;
    deg0 += pa0.x + pa0.y + pa0.z + pa0.w;
    deg1 += pa1.x + pa1.y + pa1.z + pa1.w;
    *(ushort4*)&adjL[ar * LSTR + as * 4] = w0;
    *(ushort4*)&adjL[(16 + ar) * LSTR + as * 4] = w1;
    *(int4*)&msgL[(mn +  0) * LSTR + mko] = pm0;
    *(int4*)&msgL[(mn + 32) * LSTR + mko] = pm1;
    *(int4*)&msgL[(mn + 64) * LSTR + mko] = pm2;
    *(int4*)&msgL[(mn + 96) * LSTR + mko] = pm3;
    __syncthreads();
    if (c < 31) {
      const int k0 = (c + 1) * 128;
      pa0 = *(const int4*)(aB0 + k0);
      pa1 = *(const int4*)(aB1 + k0);
      pm0 = *(const int4*)(mB0 + k0);
      pm1 = *(const int4*)(mB1 + k0);
      pm2 = *(const int4*)(mB2 + k0);
      pm3 = *(const int4*)(mB3 + k0);
    }
    for (int kk = 0; kk < 4; ++kk) {
      bf16x8 a  = *(const bf16x8*)&adjL[aOff  + kk * 32];
      bf16x8 b0 = *(const bf16x8*)&msgL[bOff0 + kk * 32];
      bf16x8 b1 = *(const bf16x8*)&msgL[bOff1 + kk * 32];
      acc0 = __builtin_amdgcn_mfma_f32_16x16x32_bf16(a, b0, acc0, 0, 0, 0);
      acc1 = __builtin_amdgcn_mfma_f32_16x16x32_bf16(a, b1, acc1, 0, 0, 0);
    }
    __syncthreads();
  }
  atomicAdd(&degS[ar], deg0);
  atomicAdd(&degS[16 + ar], deg1);
  __syncthreads();
  float* dst = aggP + (size_t)ks * NN * 128;
  for (int r = 0; r < 4; ++r) {
    const int rowL = rt * 16 + quad * 4 + r;
    const int m = m0 + rowL;
    dst[m * 128 + ct0 * 16 + l16] = acc0[r];
    dst[m * 128 + ct1 * 16 + l16] = acc1[r];
  }
  if (t < 32) degP[ks * NN + m0 + t] = degS[t];
}

// ---------------- K3: fused GRU, barrier-free GEMM phases. agg = (P0+P1)/deg combined
// in f32 at staging; A-frags (agg, nf) live in regs; B-frags read directly from the
// bf16 weights (192 KB total, L2/L1-resident) -- no per-gate LDS restaging, 1 barrier.
__global__ __launch_bounds__(256) void k3_gru(
    const float* __restrict__ nf, const float* __restrict__ aggP,
    const int* __restrict__ degP, const unsigned short* __restrict__ wihB,
    const unsigned short* __restrict__ whhB, const float* __restrict__ b_ih,
    const float* __restrict__ b_hh, const unsigned short* __restrict__ nfB,
    float* __restrict__ out) {
  __shared__ unsigned short aggL[16 * LSTR];
  __shared__ unsigned short nfL[16 * LSTR];
  const int t = threadIdx.x;
  const int m0 = blockIdx.x * 16;
  {
    const int r_ = t >> 4, c8 = (t & 15) * 8;
    const float inv =
        1.0f / fmaxf((float)(degP[m0 + r_] + degP[NN + m0 + r_]), 1.0f);
    const float* p0 = aggP + (size_t)(m0 + r_) * 128 + c8;
    const float* p1 = p0 + (size_t)NN * 128;
    float4 a0 = *(const float4*)p0, a1 = *(const float4*)(p0 + 4);
    float4 b0 = *(const float4*)p1, b1 = *(const float4*)(p1 + 4);
    float4 s0, s1;
    s0.x = (a0.x + b0.x) * inv; s0.y = (a0.y + b0.y) * inv;
    s0.z = (a0.z + b0.z) * inv; s0.w = (a0.w + b0.w) * inv;
    s1.x = (a1.x + b1.x) * inv; s1.y = (a1.y + b1.y) * inv;
    s1.z = (a1.z + b1.z) * inv; s1.w = (a1.w + b1.w) * inv;
    *(ushort4*)&aggL[r_ * LSTR + c8] = f2bf4(s0);
    *(ushort4*)&aggL[r_ * LSTR + c8 + 4] = f2bf4(s1);
    *(int4*)&nfL[r_ * LSTR + c8] = *(const int4*)&nfB[(m0 + r_) * 128 + c8];
  }
  __syncthreads();

  const int lane = t & 63, wave = t >> 6;
  const int quad = lane >> 4, l16 = lane & 15;
  const int ct0 = wave * 2, ct1 = ct0 + 1;  // 4 waves x 2 col-tiles = 128 cols

  bf16x8 aA[4], aN[4];
  for (int kk = 0; kk < 4; ++kk) {
    aA[kk] = *(const bf16x8*)&aggL[l16 * LSTR + kk * 32 + quad * 8];
    aN[kk] = *(const bf16x8*)&nfL[l16 * LSTR + kk * 32 + quad * 8];
  }

  float gate[2][4];
  const int order[3] = {0, 2, 1};  // r -> n -> z
  for (int ci = 0; ci < 3; ++ci) {
    const int c = order[ci];
    f32x4 ai[2], ah[2];
    for (int j = 0; j < 2; ++j) {
      const int o = (j ? ct1 : ct0) * 16 + l16;
      const unsigned short* wb = wihB + c * 16384 + o * 128;
      f32x4 acc = {0.f, 0.f, 0.f, 0.f};
      for (int kk = 0; kk < 4; ++kk) {
        bf16x8 b = *(const bf16x8*)&wb[kk * 32 + quad * 8];
        acc = __builtin_amdgcn_mfma_f32_16x16x32_bf16(aA[kk], b, acc, 0, 0, 0);
      }
      ai[j] = acc;
    }
    for (int j = 0; j < 2; ++j) {
      const int o = (j ? ct1 : ct0) * 16 + l16;
      const unsigned short* wb = whhB + c * 16384 + o * 128;
      f32x4 acc = {0.f, 0.f, 0.f, 0.f};
      for (int kk = 0; kk < 4; ++kk) {
        bf16x8 b = *(const bf16x8*)&wb[kk * 32 + quad * 8];
        acc = __builtin_amdgcn_mfma_f32_16x16x32_bf16(aN[kk], b, acc, 0, 0, 0);
      }
      ah[j] = acc;
    }
    for (int j = 0; j < 2; ++j) {
      const int col = (j ? ct1 : ct0) * 16 + l16;
      const float bi = b_ih[c * 128 + col];
      const float bh = b_hh[c * 128 + col];
      for (int r = 0; r < 4; ++r) {
        const float gi = ai[j][r] + bi;
        const float gh = ah[j][r] + bh;
        if (c == 0) {
          gate[j][r] = sigmoidf_(gi + gh);                 // r
        } else if (c == 2) {
          gate[j][r] = tanhf_(gi + gate[j][r] * gh);       // n = tanh(i_n + r*h_n)
        } else {
          const float z = sigmoidf_(gi + gh);
          const int m = m0 + quad * 4 + r;
          const float h = nf[m * 128 + col];
          out[m * 128 + col] = (1.0f - z) * gate[j][r] + z * h;
        }
      }
    }
  }
}

extern "C" void kernel_launch(void* const* d_in, const int* in_sizes, int n_in,
                              void* d_out, int out_size, void* d_ws, size_t ws_size,
                              hipStream_t stream) {
  const float* nf   = (const float*)d_in[0];
  const int*   adj  = (const int*)d_in[1];
  const float* wmsg = (const float*)d_in[2];
  const float* bmsg = (const float*)d_in[3];
  const float* wih  = (const float*)d_in[4];
  const float* whh  = (const float*)d_in[5];
  const float* bih  = (const float*)d_in[6];
  const float* bhh  = (const float*)d_in[7];
  float* out = (float*)d_out;

  // ws layout (all 16B-aligned): msgT 2MB | nfB 2MB | aggP 8MB | degP 64KB | wihB | whhB
  unsigned short* msgT = (unsigned short*)d_ws;            // bf16 [128][8192]
  unsigned short* nfB  = msgT + (size_t)NN * DIM;          // bf16 [8192][128]
  float* aggP          = (float*)(nfB + (size_t)NN * DIM); // f32  [2][8192][128]
  int* degP            = (int*)(aggP + (size_t)2 * NN * DIM); // i32 [2][8192]
  unsigned short* wihB = (unsigned short*)(degP + 2 * NN); // bf16 [3][128][128]
  unsigned short* whhB = wihB + 3 * DIM * DIM;             // bf16 [3][128][128]

  k1_msg<<<NN / 32, 256, 0, stream>>>(nf, wmsg, bmsg, msgT, nfB, wih, whh, wihB, whhB);
  k2_agg<<<2 * (NN / 32), 512, 0, stream>>>(adj, msgT, aggP, degP);
  k3_gru<<<NN / 16, 256, 0, stream>>>(nf, aggP, degP, wihB, whhB, bih, bhh, nfB, out);
}